// Round 5
// baseline (196.672 us; speedup 1.0000x reference)
//
#include <hip/hip_runtime.h>

namespace {

typedef unsigned int uint;
typedef unsigned short ushort_t;
typedef __attribute__((ext_vector_type(8))) short bf16x8;
typedef __attribute__((ext_vector_type(4))) float f32x4;

constexpr int N = 4, T = 2048, L = 2048;
constexpr int DQIN = 32, DQK = 64;
constexpr int LSEG = 256;                 // l per work item (4 chunks of 64)
constexpr int SEGS = L / LSEG;            // 8
constexpr int ITEMS_PER_SEG = 12 * 128;   // mn x 16-row groups
constexpr int NITEMS = SEGS * ITEMS_PER_SEG;  // 12288

// workspace layout (float-sized slots); ~13.1 MB + counters
constexpr int VI_SZ = 3 * N * 64 * L;  // ushort pairs [dim row][p][hi8|lo8], as float slots
constexpr int X_SZ = 3 * N * L;
constexpr int A_SZ = 3 * N * T;
constexpr int Y_SZ = 3 * N * T * 64;
constexpr int Z_SZ = 3 * N * T;
constexpr int CNT_INTS = 128;          // 8 counters, 64B apart

union PK8 { int i[4]; bf16x8 s; };

// =================== fused prep kernel ===================
// [0,32): Q->a,g; [32,128): binary searches; [128,512): V transform; [512,640): zero acc+counters
__global__ __launch_bounds__(256) void mm_prep(
    const float* __restrict__ ref_data, const float* __restrict__ ref_t,
    const float* __restrict__ d1, const float* __restrict__ t1,
    const float* __restrict__ d2, const float* __restrict__ t2,
    const float* __restrict__ d3, const float* __restrict__ t3,
    const float* __restrict__ Wq,
    const float* __restrict__ Wk1, const float* __restrict__ bk1,
    const float* __restrict__ Wv1, const float* __restrict__ bv1, const float* __restrict__ lt1,
    const float* __restrict__ Wk2, const float* __restrict__ bk2,
    const float* __restrict__ Wv2, const float* __restrict__ bv2, const float* __restrict__ lt2,
    const float* __restrict__ Wk3, const float* __restrict__ bk3,
    const float* __restrict__ Wv3, const float* __restrict__ bv3, const float* __restrict__ lt3,
    float* __restrict__ Aq, float* __restrict__ Gq, int* __restrict__ Cq,
    ushort_t* __restrict__ VI, float* __restrict__ X, float* __restrict__ Yacc,
    int* __restrict__ counters) {
  const int b = blockIdx.x;
  const int tid = threadIdx.x;

  if (b < 32) {
    __shared__ float sWq[DQIN * DQK];
    __shared__ float sWk[3][DQK];
    __shared__ float sbk[3][DQK];
    for (int i = tid; i < DQIN * DQK; i += 256) sWq[i] = Wq[i];
    if (tid < DQK) {
      sWk[0][tid] = Wk1[tid]; sWk[1][tid] = Wk2[tid]; sWk[2][tid] = Wk3[tid];
      sbk[0][tid] = bk1[tid]; sbk[1][tid] = bk2[tid]; sbk[2][tid] = bk3[tid];
    }
    __syncthreads();
    const int idx = b * 256 + tid;  // n*T + t
    float x[DQIN];
    const float* rp = ref_data + idx * DQIN;
#pragma unroll
    for (int i = 0; i < DQIN; i++) x[i] = rp[i];
    float qr[DQK];
#pragma unroll
    for (int j = 0; j < DQK; j += 4) {
      float4 acc4 = make_float4(0.f, 0.f, 0.f, 0.f);
#pragma unroll
      for (int i = 0; i < DQIN; i++) {
        const float4 w = *(const float4*)&sWq[i * DQK + j];
        acc4.x = fmaf(x[i], w.x, acc4.x);
        acc4.y = fmaf(x[i], w.y, acc4.y);
        acc4.z = fmaf(x[i], w.z, acc4.z);
        acc4.w = fmaf(x[i], w.w, acc4.w);
      }
      qr[j] = acc4.x; qr[j + 1] = acc4.y; qr[j + 2] = acc4.z; qr[j + 3] = acc4.w;
    }
    const float rs[3] = {__expf(-0.5f * lt1[0]), __expf(-0.5f * lt2[0]), __expf(-0.5f * lt3[0])};
#pragma unroll
    for (int m = 0; m < 3; m++) {
      float g = 0.f, h = 0.f;
#pragma unroll
      for (int j = 1; j < DQK; j++) {
        g = fmaf(qr[j], sWk[m][j - 1], g);
        h = fmaf(qr[j], sbk[m][j - 1], h);
      }
      g += sWk[m][DQK - 1];
      h += sbk[m][DQK - 1];
      Aq[m * (N * T) + idx] = (qr[0] - h) * rs[m];
      Gq[m * (N * T) + idx] = g * rs[m];
    }
  } else if (b < 128) {
    const int sidx = (b - 32) * 256 + tid;
    const int m = sidx >> 13;
    const int nt = sidx & 8191;
    const int n = nt >> 11;
    const float rt = ref_t[nt];
    const float* tml = ((m == 0) ? t1 : (m == 1 ? t2 : t3)) + n * L;
    int lo = 0, hi = L;
    while (lo < hi) {
      const int mid = (lo + hi) >> 1;
      if (tml[mid] <= rt) lo = mid + 1; else hi = mid;
    }
    Cq[m * 8192 + nt] = lo;
  } else if (b < 512) {
    const int vb = b - 128;          // 0..383
    const int mn = vb >> 5;          // m*N+n
    const int m = mn >> 2, n = mn & 3;
    const int lseg0 = (vb & 31) * 64;
    const float* dm = (m == 0) ? d1 : (m == 1 ? d2 : d3);
    const float* Wv = (m == 0) ? Wv1 : (m == 1 ? Wv2 : Wv3);
    const float* bv = (m == 0) ? bv1 : (m == 1 ? bv2 : bv3);
    const int cdim = tid & 63;
    const int qq = tid >> 6;
    const int l0 = lseg0 + qq * 16;

    float Wc[32];
#pragma unroll
    for (int i = 0; i < 32; i++) Wc[i] = Wv[i * 64 + cdim];
    const float bvc = bv[cdim];

    uint hi16[16], lo16[16];
#pragma unroll 4
    for (int k = 0; k < 16; k++) {
      const float* dp = dm + (size_t)(n * L + l0 + k) * 34;
      float acc = bvc;
#pragma unroll
      for (int i = 0; i < 32; i++) acc = fmaf(dp[i], Wc[i], acc);
      uint u = __float_as_uint(acc);
      uint h = (u + 0x7fffu + ((u >> 16) & 1u)) & 0xffff0000u;
      float res = acc - __uint_as_float(h);
      uint ul = __float_as_uint(res);
      uint hl = (ul + 0x7fffu + ((ul >> 16) & 1u)) >> 16;
      hi16[k] = h >> 16;
      lo16[k] = hl;
    }
    int pkh[8], pkl[8];
#pragma unroll
    for (int p = 0; p < 8; p++) {
      pkh[p] = (int)(hi16[2 * p] | (hi16[2 * p + 1] << 16));
      pkl[p] = (int)(lo16[2 * p] | (lo16[2 * p + 1] << 16));
    }
    ushort_t* dst = VI + (size_t)(mn * 64 + cdim) * (2 * L) + (l0 >> 3) * 16;
    *(int4*)dst = make_int4(pkh[0], pkh[1], pkh[2], pkh[3]);
    *(int4*)(dst + 8) = make_int4(pkl[0], pkl[1], pkl[2], pkl[3]);
    *(int4*)(dst + 16) = make_int4(pkh[4], pkh[5], pkh[6], pkh[7]);
    *(int4*)(dst + 24) = make_int4(pkl[4], pkl[5], pkl[6], pkl[7]);

    if (tid < 64) {
      const int l = lseg0 + tid;
      X[mn * L + l] = dm[(size_t)(n * L + l) * 34 + 33];
    }
  } else {
    float4* dst = (float4*)Yacc;
    const float4 zz = make_float4(0.f, 0.f, 0.f, 0.f);
    const int stride = 128 * 256;
    for (int i = (b - 512) * 256 + tid; i < (Y_SZ + Z_SZ) / 4; i += stride) dst[i] = zz;
    if (b == 512 && tid < CNT_INTS) counters[tid] = 0;
  }
}

// =================== main attention kernel (persistent, dynamic wave queue) ===================
struct Buf {
  bf16x8 h[8];   // [kk*4+ct]
  bf16x8 l[8];
  float4 x[4];   // [kk*2+half]
};

struct Meta {
  int c, lBeg, lEnd, mnL, tbase;
  float a, g;
  bool act;
};

__device__ inline int pop_raw(int* cnt) {
  int v = 0;
  if ((threadIdx.x & 63) == 0) v = atomicAdd(cnt, 1);
  return __shfl(v, 0, 64);
}

__device__ inline Meta load_meta(int id, const int* __restrict__ Cq,
                                 const float* __restrict__ Aq, const float* __restrict__ Gq,
                                 int m16) {
  Meta M;
  M.act = false;
  M.c = 0; M.lBeg = 0; M.lEnd = 0; M.mnL = 0; M.tbase = 0; M.a = 0.f; M.g = 0.f;
  if (id < NITEMS) {
    const int seg = id / ITEMS_PER_SEG;      // items ordered seg-major: heavy first
    const int rem = id - seg * ITEMS_PER_SEG;
    const int mn = rem >> 7;
    const int rgp = rem & 127;
    const int tbase = mn * T + rgp * 16;
    const int c = Cq[tbase + m16];
    const int cmaxw = __shfl(c, 15, 64);     // c monotone in t
    const int lBeg = seg * LSEG;
    M.c = c; M.lBeg = lBeg;
    M.lEnd = min(lBeg + LSEG, cmaxw);
    M.mnL = mn * L; M.tbase = tbase;
    if (cmaxw > lBeg) {
      M.act = true;
      M.a = Aq[tbase + m16];
      M.g = Gq[tbase + m16];
    }
  }
  return M;
}

__device__ inline void load_buf(Buf& B, const ushort_t* vbase, const float* xp, int base, int q) {
#pragma unroll
  for (int kk = 0; kk < 2; kk++) {
    const int p = ((base + kk * 32) >> 3) + q;
#pragma unroll
    for (int ct = 0; ct < 4; ct++) {
      const ushort_t* ptr = vbase + (size_t)ct * (16 * 2 * L) + p * 16;
      B.h[kk * 4 + ct] = *(const bf16x8*)ptr;
      B.l[kk * 4 + ct] = *(const bf16x8*)(ptr + 8);
    }
    const int k0 = base + kk * 32 + q * 8;
    B.x[kk * 2] = *(const float4*)&xp[k0];
    B.x[kk * 2 + 1] = *(const float4*)&xp[k0 + 4];
  }
}

__device__ inline void step(const Buf& B, int base, int q, int c, int cmin,
                            float a, float g, f32x4 acc[4], float& z) {
  const bool interior = (base + 64 <= cmin);  // wave-uniform: all 16 rows fully active
#pragma unroll
  for (int kk = 0; kk < 2; kk++) {
    const int k0 = base + kk * 32 + q * 8;
    const float4 xa = B.x[kk * 2], xb = B.x[kk * 2 + 1];
    const float xs[8] = {xa.x, xa.y, xa.z, xa.w, xb.x, xb.y, xb.z, xb.w};
    float w[8];
    if (interior) {
#pragma unroll
      for (int j = 0; j < 8; j++) {
        const float d = fmaf(-g, xs[j], a);
        w[j] = __expf(-d * d);
        z += w[j];
      }
    } else {
#pragma unroll
      for (int j = 0; j < 8; j++) {
        const float d = fmaf(-g, xs[j], a);
        const float e = __expf(-d * d);
        w[j] = (k0 + j < c) ? e : 0.f;
        z += w[j];
      }
    }
    PK8 ph, pl;
#pragma unroll
    for (int p2 = 0; p2 < 4; p2++) {
      const uint u0 = __float_as_uint(w[2 * p2]);
      const uint u1 = __float_as_uint(w[2 * p2 + 1]);
      const uint h0 = u0 & 0xffff0000u, h1 = u1 & 0xffff0000u;
      const float l0f = w[2 * p2] - __uint_as_float(h0);
      const float l1f = w[2 * p2 + 1] - __uint_as_float(h1);
      ph.i[p2] = (int)((h0 >> 16) | h1);
      pl.i[p2] = (int)((__float_as_uint(l0f) >> 16) | (__float_as_uint(l1f) & 0xffff0000u));
    }
    const bf16x8 ahi = ph.s, alo = pl.s;
#pragma unroll
    for (int ct = 0; ct < 4; ct++) {
      acc[ct] = __builtin_amdgcn_mfma_f32_16x16x32_bf16(ahi, B.h[kk * 4 + ct], acc[ct], 0, 0, 0);
      acc[ct] = __builtin_amdgcn_mfma_f32_16x16x32_bf16(ahi, B.l[kk * 4 + ct], acc[ct], 0, 0, 0);
      acc[ct] = __builtin_amdgcn_mfma_f32_16x16x32_bf16(alo, B.h[kk * 4 + ct], acc[ct], 0, 0, 0);
    }
  }
}

__device__ inline void body(const Meta& M, const ushort_t* __restrict__ VI,
                            const float* __restrict__ X, int q, int m16,
                            f32x4 acc[4], float& z) {
  const int cmin = __shfl(M.c, 0, 64);
  const ushort_t* vbase = VI + (size_t)M.mnL * 128 + (size_t)m16 * (2 * L);
  const float* xp = X + M.mnL;
  const int nch = (M.lEnd - M.lBeg + 63) >> 6;  // 1..4

  Buf b0, b1;
  int base = M.lBeg, ch = 0;
  load_buf(b0, vbase, xp, base, q);
  for (; ch + 2 <= nch; ch += 2, base += 128) {
    load_buf(b1, vbase, xp, base + 64, q);
    step(b0, base, q, M.c, cmin, M.a, M.g, acc, z);
    if (ch + 2 < nch) load_buf(b0, vbase, xp, base + 128, q);
    step(b1, base + 64, q, M.c, cmin, M.a, M.g, acc, z);
  }
  if (ch < nch) step(b0, base, q, M.c, cmin, M.a, M.g, acc, z);
}

__device__ inline void epilogue(const Meta& M, const f32x4 acc[4], float z,
                                int q, int m16, int lane,
                                float* __restrict__ Yacc, float* __restrict__ Zacc) {
  float zz = z;
  zz += __shfl_xor(zz, 16, 64);
  zz += __shfl_xor(zz, 32, 64);
  const int orow0 = M.tbase + q * 4;
#pragma unroll
  for (int ct = 0; ct < 4; ct++) {
#pragma unroll
    for (int rr = 0; rr < 4; rr++) {
      const float v = acc[ct][rr];
      if (v != 0.f)  // inactive rows accumulate exact 0.0 -> skip the line
        unsafeAtomicAdd(&Yacc[(size_t)(orow0 + rr) * 64 + ct * 16 + m16], v);
    }
  }
  if (lane < 16 && zz != 0.f) unsafeAtomicAdd(&Zacc[M.tbase + lane], zz);
}

__global__ __launch_bounds__(256) void mm_attn_main(
    const ushort_t* __restrict__ VI, const float* __restrict__ X,
    const float* __restrict__ Aq, const float* __restrict__ Gq, const int* __restrict__ Cq,
    float* __restrict__ Yacc, float* __restrict__ Zacc, int* __restrict__ counters) {
  const int lane = threadIdx.x & 63;
  const int q = lane >> 4;
  const int m16 = lane & 15;
  const int cid = ((blockIdx.x << 2) + (threadIdx.x >> 6)) & 7;  // stripe waves over 8 counters
  int* cnt = counters + cid * 16;                                 // 64B apart

  int id = pop_raw(cnt) * 8 + cid;
  Meta M = load_meta(id, Cq, Aq, Gq, m16);

  while (id < NITEMS) {
    const int nid = pop_raw(cnt) * 8 + cid;  // pop next early; latency hides under body
    f32x4 acc[4];
    float z = 0.f;
    if (M.act) {
#pragma unroll
      for (int ct = 0; ct < 4; ct++) acc[ct] = (f32x4){0.f, 0.f, 0.f, 0.f};
      body(M, VI, X, q, m16, acc, z);
    }
    const Meta M2 = load_meta(nid, Cq, Aq, Gq, m16);  // prefetch next meta before epilogue
    if (M.act) epilogue(M, acc, z, q, m16, lane, Yacc, Zacc);
    M = M2;
    id = nid;
  }
}

// =================== finalize: out = Y / (Z + (L - c)), float4 ===================
__global__ __launch_bounds__(256) void mm_finalize(
    const float4* __restrict__ Y4, const float* __restrict__ Zacc,
    const int* __restrict__ Cq, float4* __restrict__ out4) {
  const int i = blockIdx.x * 256 + threadIdx.x;  // over 3*N*T*16 float4s
  const int row = i >> 4;
  const float Zr = Zacc[row] + (float)(L - Cq[row]);
  const float inv = 1.0f / Zr;
  const float4 y = Y4[i];
  out4[i] = make_float4(y.x * inv, y.y * inv, y.z * inv, y.w * inv);
}

}  // namespace

extern "C" void kernel_launch(void* const* d_in, const int* in_sizes, int n_in,
                              void* d_out, int out_size, void* d_ws, size_t ws_size,
                              hipStream_t stream) {
  const float* ref_data = (const float*)d_in[0];
  const float* ref_t = (const float*)d_in[1];
  const float* m1_data = (const float*)d_in[2];
  const float* m1_t = (const float*)d_in[3];
  const float* m2_data = (const float*)d_in[4];
  const float* m2_t = (const float*)d_in[5];
  const float* m3_data = (const float*)d_in[6];
  const float* m3_t = (const float*)d_in[7];
  const float* Wq = (const float*)d_in[8];
  const float* Wk1 = (const float*)d_in[9];
  const float* bk1 = (const float*)d_in[10];
  const float* Wv1 = (const float*)d_in[11];
  const float* bv1 = (const float*)d_in[12];
  const float* lt1 = (const float*)d_in[13];
  const float* Wk2 = (const float*)d_in[14];
  const float* bk2 = (const float*)d_in[15];
  const float* Wv2 = (const float*)d_in[16];
  const float* bv2 = (const float*)d_in[17];
  const float* lt2 = (const float*)d_in[18];
  const float* Wk3 = (const float*)d_in[19];
  const float* bk3 = (const float*)d_in[20];
  const float* Wv3 = (const float*)d_in[21];
  const float* bv3 = (const float*)d_in[22];
  const float* lt3 = (const float*)d_in[23];

  float* ws = (float*)d_ws;
  ushort_t* VI = (ushort_t*)ws;                 // VI_SZ float slots
  float* Xw = ws + VI_SZ;                       // X_SZ
  float* Aq = Xw + X_SZ;                        // A_SZ
  float* Gq = Aq + A_SZ;                        // A_SZ
  int* Cq = (int*)(Gq + A_SZ);                  // A_SZ
  float* Yacc = (float*)(Cq + A_SZ);            // Y_SZ
  float* Zacc = Yacc + Y_SZ;                    // Z_SZ
  int* counters = (int*)(Zacc + Z_SZ);          // CNT_INTS

  mm_prep<<<dim3(640), dim3(256), 0, stream>>>(
      ref_data, ref_t, m1_data, m1_t, m2_data, m2_t, m3_data, m3_t, Wq,
      Wk1, bk1, Wv1, bv1, lt1, Wk2, bk2, Wv2, bv2, lt2, Wk3, bk3, Wv3, bv3, lt3,
      Aq, Gq, Cq, VI, Xw, Yacc, counters);
  mm_attn_main<<<dim3(1024), dim3(256), 0, stream>>>(
      VI, Xw, Aq, Gq, Cq, Yacc, Zacc, counters);
  mm_finalize<<<dim3((3 * N * T * 16) / 256), dim3(256), 0, stream>>>(
      (const float4*)Yacc, Zacc, Cq, (float4*)d_out);
}

// Round 6
// 178.857 us; speedup vs baseline: 1.0996x; 1.0996x over previous
//
#include <hip/hip_runtime.h>

namespace {

typedef unsigned int uint;
typedef unsigned short ushort_t;
typedef __attribute__((ext_vector_type(8))) short bf16x8;
typedef __attribute__((ext_vector_type(4))) float f32x4;

constexpr int N = 4, T = 2048, L = 2048;
constexpr int DQIN = 32, DQK = 64;

// workspace layout (float-sized slots); ~12.8 MB
constexpr int VI_SZ = 3 * N * 64 * L;  // ushort pairs [dim row][p][hi8|lo8], as float slots
constexpr int X_SZ = 3 * N * L;
constexpr int A_SZ = 3 * N * T;

union PK8 { int i[4]; bf16x8 s; };

// =================== fused prep kernel ===================
// [0,32): Q->a,g; [32,128): binary searches; [128,512): V transform
__global__ __launch_bounds__(256) void mm_prep(
    const float* __restrict__ ref_data, const float* __restrict__ ref_t,
    const float* __restrict__ d1, const float* __restrict__ t1,
    const float* __restrict__ d2, const float* __restrict__ t2,
    const float* __restrict__ d3, const float* __restrict__ t3,
    const float* __restrict__ Wq,
    const float* __restrict__ Wk1, const float* __restrict__ bk1,
    const float* __restrict__ Wv1, const float* __restrict__ bv1, const float* __restrict__ lt1,
    const float* __restrict__ Wk2, const float* __restrict__ bk2,
    const float* __restrict__ Wv2, const float* __restrict__ bv2, const float* __restrict__ lt2,
    const float* __restrict__ Wk3, const float* __restrict__ bk3,
    const float* __restrict__ Wv3, const float* __restrict__ bv3, const float* __restrict__ lt3,
    float* __restrict__ Aq, float* __restrict__ Gq, int* __restrict__ Cq,
    ushort_t* __restrict__ VI, float* __restrict__ X) {
  const int b = blockIdx.x;
  const int tid = threadIdx.x;

  if (b < 32) {
    __shared__ float sWq[DQIN * DQK];
    __shared__ float sWk[3][DQK];
    __shared__ float sbk[3][DQK];
    for (int i = tid; i < DQIN * DQK; i += 256) sWq[i] = Wq[i];
    if (tid < DQK) {
      sWk[0][tid] = Wk1[tid]; sWk[1][tid] = Wk2[tid]; sWk[2][tid] = Wk3[tid];
      sbk[0][tid] = bk1[tid]; sbk[1][tid] = bk2[tid]; sbk[2][tid] = bk3[tid];
    }
    __syncthreads();
    const int idx = b * 256 + tid;  // n*T + t
    float x[DQIN];
    const float* rp = ref_data + idx * DQIN;
#pragma unroll
    for (int i = 0; i < DQIN; i++) x[i] = rp[i];
    float qr[DQK];
#pragma unroll
    for (int j = 0; j < DQK; j += 4) {
      float4 acc4 = make_float4(0.f, 0.f, 0.f, 0.f);
#pragma unroll
      for (int i = 0; i < DQIN; i++) {
        const float4 w = *(const float4*)&sWq[i * DQK + j];
        acc4.x = fmaf(x[i], w.x, acc4.x);
        acc4.y = fmaf(x[i], w.y, acc4.y);
        acc4.z = fmaf(x[i], w.z, acc4.z);
        acc4.w = fmaf(x[i], w.w, acc4.w);
      }
      qr[j] = acc4.x; qr[j + 1] = acc4.y; qr[j + 2] = acc4.z; qr[j + 3] = acc4.w;
    }
    const float rs[3] = {__expf(-0.5f * lt1[0]), __expf(-0.5f * lt2[0]), __expf(-0.5f * lt3[0])};
#pragma unroll
    for (int m = 0; m < 3; m++) {
      float g = 0.f, h = 0.f;
#pragma unroll
      for (int j = 1; j < DQK; j++) {
        g = fmaf(qr[j], sWk[m][j - 1], g);
        h = fmaf(qr[j], sbk[m][j - 1], h);
      }
      g += sWk[m][DQK - 1];
      h += sbk[m][DQK - 1];
      Aq[m * (N * T) + idx] = (qr[0] - h) * rs[m];
      Gq[m * (N * T) + idx] = g * rs[m];
    }
  } else if (b < 128) {
    const int sidx = (b - 32) * 256 + tid;
    const int m = sidx >> 13;
    const int nt = sidx & 8191;
    const int n = nt >> 11;
    const float rt = ref_t[nt];
    const float* tml = ((m == 0) ? t1 : (m == 1 ? t2 : t3)) + n * L;
    int lo = 0, hi = L;
    while (lo < hi) {
      const int mid = (lo + hi) >> 1;
      if (tml[mid] <= rt) lo = mid + 1; else hi = mid;
    }
    Cq[m * 8192 + nt] = lo;
  } else {
    const int vb = b - 128;          // 0..383
    const int mn = vb >> 5;          // m*N+n
    const int m = mn >> 2, n = mn & 3;
    const int lseg0 = (vb & 31) * 64;
    const float* dm = (m == 0) ? d1 : (m == 1 ? d2 : d3);
    const float* Wv = (m == 0) ? Wv1 : (m == 1 ? Wv2 : Wv3);
    const float* bv = (m == 0) ? bv1 : (m == 1 ? bv2 : bv3);
    const int cdim = tid & 63;
    const int qq = tid >> 6;
    const int l0 = lseg0 + qq * 16;

    float Wc[32];
#pragma unroll
    for (int i = 0; i < 32; i++) Wc[i] = Wv[i * 64 + cdim];
    const float bvc = bv[cdim];

    uint hi16[16], lo16[16];
#pragma unroll 4
    for (int k = 0; k < 16; k++) {
      const float* dp = dm + (size_t)(n * L + l0 + k) * 34;
      float acc = bvc;
#pragma unroll
      for (int i = 0; i < 32; i++) acc = fmaf(dp[i], Wc[i], acc);
      uint u = __float_as_uint(acc);
      uint h = (u + 0x7fffu + ((u >> 16) & 1u)) & 0xffff0000u;
      float res = acc - __uint_as_float(h);
      uint ul = __float_as_uint(res);
      uint hl = (ul + 0x7fffu + ((ul >> 16) & 1u)) >> 16;
      hi16[k] = h >> 16;
      lo16[k] = hl;
    }
    int pkh[8], pkl[8];
#pragma unroll
    for (int p = 0; p < 8; p++) {
      pkh[p] = (int)(hi16[2 * p] | (hi16[2 * p + 1] << 16));
      pkl[p] = (int)(lo16[2 * p] | (lo16[2 * p + 1] << 16));
    }
    ushort_t* dst = VI + (size_t)(mn * 64 + cdim) * (2 * L) + (l0 >> 3) * 16;
    *(int4*)dst = make_int4(pkh[0], pkh[1], pkh[2], pkh[3]);
    *(int4*)(dst + 8) = make_int4(pkl[0], pkl[1], pkl[2], pkl[3]);
    *(int4*)(dst + 16) = make_int4(pkh[4], pkh[5], pkh[6], pkh[7]);
    *(int4*)(dst + 24) = make_int4(pkl[4], pkl[5], pkl[6], pkl[7]);

    if (tid < 64) {
      const int l = lseg0 + tid;
      X[mn * L + l] = dm[(size_t)(n * L + l) * 34 + 33];
    }
  }
}

// =================== main attention kernel ===================
// block = one 16-row group, full l-range; 4 waves take contiguous quarters of the
// chunk list; LDS merge; no atomics anywhere. 32-l half-chunk register pipeline.
struct Buf {
  bf16x8 h[4];   // V-hi fragment per ct
  bf16x8 l[4];   // V-lo fragment per ct
  float4 x0, x1; // x for k0..k0+7
};

__device__ inline void load_buf(Buf& B, const ushort_t* vbase, const float* xp, int hc, int q) {
  const int p = hc * 4 + q;  // 8-l group index
#pragma unroll
  for (int ct = 0; ct < 4; ct++) {
    const ushort_t* ptr = vbase + (size_t)ct * (16 * 2 * L) + p * 16;
    B.h[ct] = *(const bf16x8*)ptr;
    B.l[ct] = *(const bf16x8*)(ptr + 8);
  }
  const int k0 = hc * 32 + q * 8;
  B.x0 = *(const float4*)&xp[k0];
  B.x1 = *(const float4*)&xp[k0 + 4];
}

__device__ inline void step(const Buf& B, int hc, int q, int c, int cmin,
                            float a, float g, f32x4 acc[4], float& z) {
  const int base = hc * 32;
  const int k0 = base + q * 8;
  const float xs[8] = {B.x0.x, B.x0.y, B.x0.z, B.x0.w, B.x1.x, B.x1.y, B.x1.z, B.x1.w};
  float w[8];
  if (base + 32 <= cmin) {  // wave-uniform: all 16 rows fully active in this half-chunk
#pragma unroll
    for (int j = 0; j < 8; j++) {
      const float d = fmaf(-g, xs[j], a);
      w[j] = __expf(-d * d);
      z += w[j];
    }
  } else {
#pragma unroll
    for (int j = 0; j < 8; j++) {
      const float d = fmaf(-g, xs[j], a);
      const float e = __expf(-d * d);
      w[j] = (k0 + j < c) ? e : 0.f;
      z += w[j];
    }
  }
  PK8 ph, pl;
#pragma unroll
  for (int p2 = 0; p2 < 4; p2++) {
    const uint u0 = __float_as_uint(w[2 * p2]);
    const uint u1 = __float_as_uint(w[2 * p2 + 1]);
    const uint h0 = u0 & 0xffff0000u, h1 = u1 & 0xffff0000u;
    const float l0f = w[2 * p2] - __uint_as_float(h0);
    const float l1f = w[2 * p2 + 1] - __uint_as_float(h1);
    ph.i[p2] = (int)((h0 >> 16) | h1);
    pl.i[p2] = (int)((__float_as_uint(l0f) >> 16) | (__float_as_uint(l1f) & 0xffff0000u));
  }
  const bf16x8 ahi = ph.s, alo = pl.s;
#pragma unroll
  for (int ct = 0; ct < 4; ct++) {
    acc[ct] = __builtin_amdgcn_mfma_f32_16x16x32_bf16(ahi, B.h[ct], acc[ct], 0, 0, 0);
    acc[ct] = __builtin_amdgcn_mfma_f32_16x16x32_bf16(ahi, B.l[ct], acc[ct], 0, 0, 0);
    acc[ct] = __builtin_amdgcn_mfma_f32_16x16x32_bf16(alo, B.h[ct], acc[ct], 0, 0, 0);
  }
}

// grid: 12*128 = 1536 blocks; mn = b%12 (XCD L2 locality); rowgroup order
// interleaves light/heavy so per-CU load is balanced (c_i + c_{127-i} ~ const).
__global__ __launch_bounds__(256) void mm_attn_main(
    const ushort_t* __restrict__ VI, const float* __restrict__ X,
    const float* __restrict__ Aq, const float* __restrict__ Gq, const int* __restrict__ Cq,
    float* __restrict__ out) {
  __shared__ float sAcc[4][16][68];  // [wave][row][col], stride 68 breaks conflicts
  __shared__ float sZ[4][16];
  __shared__ int sC[16];

  const int b = blockIdx.x;
  const int mn = b % 12;
  const int r = b / 12;  // 0..127
  const int rg = (r & 1) ? (127 - (r >> 1)) : (r >> 1);
  const int tbase = mn * T + rg * 16;

  const int tid = threadIdx.x;
  const int lane = tid & 63;
  const int w = tid >> 6;
  const int q = lane >> 4;
  const int m16 = lane & 15;

  const int c = Cq[tbase + m16];
  const int cmax = __shfl(c, 15, 64);  // c monotone in t
  const int cmin = __shfl(c, 0, 64);
  const float a = Aq[tbase + m16];
  const float g = Gq[tbase + m16];

  if (tid < 16) sC[tid] = c;  // w==0, m16==tid

  f32x4 acc[4];
#pragma unroll
  for (int ct = 0; ct < 4; ct++) acc[ct] = (f32x4){0.f, 0.f, 0.f, 0.f};
  float z = 0.f;

  // wave w takes chunk quarter [s0, s1) of [0, nch); process as 32-l half-chunks
  const int nch = (cmax + 63) >> 6;
  const int s0 = (w * nch) >> 2;
  const int s1 = ((w + 1) * nch) >> 2;
  int hc = 2 * s0;
  const int hcE = 2 * s1;

  const ushort_t* vbase = VI + (size_t)(mn * 64 + m16) * (2 * L);
  const float* xp = X + mn * L;

  if (hc < hcE) {
    Buf A, B2;
    load_buf(A, vbase, xp, hc, q);
    for (; hc + 2 <= hcE; hc += 2) {
      load_buf(B2, vbase, xp, hc + 1, q);
      step(A, hc, q, c, cmin, a, g, acc, z);
      if (hc + 2 < hcE) load_buf(A, vbase, xp, hc + 2, q);
      step(B2, hc + 1, q, c, cmin, a, g, acc, z);
    }
    if (hc < hcE) step(A, hc, q, c, cmin, a, g, acc, z);
  }

  // merge: z across q replicas, acc across waves via LDS
  z += __shfl_xor(z, 16, 64);
  z += __shfl_xor(z, 32, 64);
  if (lane < 16) sZ[w][lane] = z;
#pragma unroll
  for (int ct = 0; ct < 4; ct++) {
#pragma unroll
    for (int rr = 0; rr < 4; rr++) {
      sAcc[w][q * 4 + rr][ct * 16 + m16] = acc[ct][rr];
    }
  }
  __syncthreads();

  const int row = tid >> 4;        // 0..15
  const int col = (tid & 15) * 4;  // 0..60
  float4 s0v = *(const float4*)&sAcc[0][row][col];
  const float4 s1v = *(const float4*)&sAcc[1][row][col];
  const float4 s2v = *(const float4*)&sAcc[2][row][col];
  const float4 s3v = *(const float4*)&sAcc[3][row][col];
  const float Zr = sZ[0][row] + sZ[1][row] + sZ[2][row] + sZ[3][row] + (float)(L - sC[row]);
  const float inv = 1.0f / Zr;
  s0v.x = (s0v.x + s1v.x + s2v.x + s3v.x) * inv;
  s0v.y = (s0v.y + s1v.y + s2v.y + s3v.y) * inv;
  s0v.z = (s0v.z + s1v.z + s2v.z + s3v.z) * inv;
  s0v.w = (s0v.w + s1v.w + s2v.w + s3v.w) * inv;
  *(float4*)&out[(size_t)(tbase + row) * 64 + col] = s0v;
}

}  // namespace

extern "C" void kernel_launch(void* const* d_in, const int* in_sizes, int n_in,
                              void* d_out, int out_size, void* d_ws, size_t ws_size,
                              hipStream_t stream) {
  const float* ref_data = (const float*)d_in[0];
  const float* ref_t = (const float*)d_in[1];
  const float* m1_data = (const float*)d_in[2];
  const float* m1_t = (const float*)d_in[3];
  const float* m2_data = (const float*)d_in[4];
  const float* m2_t = (const float*)d_in[5];
  const float* m3_data = (const float*)d_in[6];
  const float* m3_t = (const float*)d_in[7];
  const float* Wq = (const float*)d_in[8];
  const float* Wk1 = (const float*)d_in[9];
  const float* bk1 = (const float*)d_in[10];
  const float* Wv1 = (const float*)d_in[11];
  const float* bv1 = (const float*)d_in[12];
  const float* lt1 = (const float*)d_in[13];
  const float* Wk2 = (const float*)d_in[14];
  const float* bk2 = (const float*)d_in[15];
  const float* Wv2 = (const float*)d_in[16];
  const float* bv2 = (const float*)d_in[17];
  const float* lt2 = (const float*)d_in[18];
  const float* Wk3 = (const float*)d_in[19];
  const float* bk3 = (const float*)d_in[20];
  const float* Wv3 = (const float*)d_in[21];
  const float* bv3 = (const float*)d_in[22];
  const float* lt3 = (const float*)d_in[23];

  float* ws = (float*)d_ws;
  ushort_t* VI = (ushort_t*)ws;                 // VI_SZ float slots
  float* Xw = ws + VI_SZ;                       // X_SZ
  float* Aq = Xw + X_SZ;                        // A_SZ
  float* Gq = Aq + A_SZ;                        // A_SZ
  int* Cq = (int*)(Gq + A_SZ);                  // A_SZ

  mm_prep<<<dim3(512), dim3(256), 0, stream>>>(
      ref_data, ref_t, m1_data, m1_t, m2_data, m2_t, m3_data, m3_t, Wq,
      Wk1, bk1, Wv1, bv1, lt1, Wk2, bk2, Wv2, bv2, lt2, Wk3, bk3, Wv3, bv3, lt3,
      Aq, Gq, Cq, VI, Xw);
  mm_attn_main<<<dim3(12 * 128), dim3(256), 0, stream>>>(
      VI, Xw, Aq, Gq, Cq, (float*)d_out);
}

// Round 7
// 174.770 us; speedup vs baseline: 1.1253x; 1.0234x over previous
//
#include <hip/hip_runtime.h>

namespace {

typedef unsigned int uint;
typedef unsigned short ushort_t;
typedef __attribute__((ext_vector_type(8))) short bf16x8;
typedef __attribute__((ext_vector_type(4))) float f32x4;

constexpr int N = 4, T = 2048, L = 2048;
constexpr int DQIN = 32, DQK = 64;

// workspace layout (float-sized slots); ~12.8 MB
constexpr int VI_SZ = 3 * N * 64 * L;  // ushort pairs [dim row][8l-group][hi8|lo8], as float slots
constexpr int X_SZ = 3 * N * L;
constexpr int A_SZ = 3 * N * T;

union PK8 { int i[4]; bf16x8 s; };

// =================== fused prep kernel (unchanged from round 6) ===================
__global__ __launch_bounds__(256) void mm_prep(
    const float* __restrict__ ref_data, const float* __restrict__ ref_t,
    const float* __restrict__ d1, const float* __restrict__ t1,
    const float* __restrict__ d2, const float* __restrict__ t2,
    const float* __restrict__ d3, const float* __restrict__ t3,
    const float* __restrict__ Wq,
    const float* __restrict__ Wk1, const float* __restrict__ bk1,
    const float* __restrict__ Wv1, const float* __restrict__ bv1, const float* __restrict__ lt1,
    const float* __restrict__ Wk2, const float* __restrict__ bk2,
    const float* __restrict__ Wv2, const float* __restrict__ bv2, const float* __restrict__ lt2,
    const float* __restrict__ Wk3, const float* __restrict__ bk3,
    const float* __restrict__ Wv3, const float* __restrict__ bv3, const float* __restrict__ lt3,
    float* __restrict__ Aq, float* __restrict__ Gq, int* __restrict__ Cq,
    ushort_t* __restrict__ VI, float* __restrict__ X) {
  const int b = blockIdx.x;
  const int tid = threadIdx.x;

  if (b < 32) {
    __shared__ float sWq[DQIN * DQK];
    __shared__ float sWk[3][DQK];
    __shared__ float sbk[3][DQK];
    for (int i = tid; i < DQIN * DQK; i += 256) sWq[i] = Wq[i];
    if (tid < DQK) {
      sWk[0][tid] = Wk1[tid]; sWk[1][tid] = Wk2[tid]; sWk[2][tid] = Wk3[tid];
      sbk[0][tid] = bk1[tid]; sbk[1][tid] = bk2[tid]; sbk[2][tid] = bk3[tid];
    }
    __syncthreads();
    const int idx = b * 256 + tid;  // n*T + t
    float x[DQIN];
    const float* rp = ref_data + idx * DQIN;
#pragma unroll
    for (int i = 0; i < DQIN; i++) x[i] = rp[i];
    float qr[DQK];
#pragma unroll
    for (int j = 0; j < DQK; j += 4) {
      float4 acc4 = make_float4(0.f, 0.f, 0.f, 0.f);
#pragma unroll
      for (int i = 0; i < DQIN; i++) {
        const float4 w = *(const float4*)&sWq[i * DQK + j];
        acc4.x = fmaf(x[i], w.x, acc4.x);
        acc4.y = fmaf(x[i], w.y, acc4.y);
        acc4.z = fmaf(x[i], w.z, acc4.z);
        acc4.w = fmaf(x[i], w.w, acc4.w);
      }
      qr[j] = acc4.x; qr[j + 1] = acc4.y; qr[j + 2] = acc4.z; qr[j + 3] = acc4.w;
    }
    const float rs[3] = {__expf(-0.5f * lt1[0]), __expf(-0.5f * lt2[0]), __expf(-0.5f * lt3[0])};
#pragma unroll
    for (int m = 0; m < 3; m++) {
      float g = 0.f, h = 0.f;
#pragma unroll
      for (int j = 1; j < DQK; j++) {
        g = fmaf(qr[j], sWk[m][j - 1], g);
        h = fmaf(qr[j], sbk[m][j - 1], h);
      }
      g += sWk[m][DQK - 1];
      h += sbk[m][DQK - 1];
      Aq[m * (N * T) + idx] = (qr[0] - h) * rs[m];
      Gq[m * (N * T) + idx] = g * rs[m];
    }
  } else if (b < 128) {
    const int sidx = (b - 32) * 256 + tid;
    const int m = sidx >> 13;
    const int nt = sidx & 8191;
    const int n = nt >> 11;
    const float rt = ref_t[nt];
    const float* tml = ((m == 0) ? t1 : (m == 1 ? t2 : t3)) + n * L;
    int lo = 0, hi = L;
    while (lo < hi) {
      const int mid = (lo + hi) >> 1;
      if (tml[mid] <= rt) lo = mid + 1; else hi = mid;
    }
    Cq[m * 8192 + nt] = lo;
  } else {
    const int vb = b - 128;          // 0..383
    const int mn = vb >> 5;          // m*N+n
    const int m = mn >> 2, n = mn & 3;
    const int lseg0 = (vb & 31) * 64;
    const float* dm = (m == 0) ? d1 : (m == 1 ? d2 : d3);
    const float* Wv = (m == 0) ? Wv1 : (m == 1 ? Wv2 : Wv3);
    const float* bv = (m == 0) ? bv1 : (m == 1 ? bv2 : bv3);
    const int cdim = tid & 63;
    const int qq = tid >> 6;
    const int l0 = lseg0 + qq * 16;

    float Wc[32];
#pragma unroll
    for (int i = 0; i < 32; i++) Wc[i] = Wv[i * 64 + cdim];
    const float bvc = bv[cdim];

    uint hi16[16], lo16[16];
#pragma unroll 4
    for (int k = 0; k < 16; k++) {
      const float* dp = dm + (size_t)(n * L + l0 + k) * 34;
      float acc = bvc;
#pragma unroll
      for (int i = 0; i < 32; i++) acc = fmaf(dp[i], Wc[i], acc);
      uint u = __float_as_uint(acc);
      uint h = (u + 0x7fffu + ((u >> 16) & 1u)) & 0xffff0000u;
      float res = acc - __uint_as_float(h);
      uint ul = __float_as_uint(res);
      uint hl = (ul + 0x7fffu + ((ul >> 16) & 1u)) >> 16;
      hi16[k] = h >> 16;
      lo16[k] = hl;
    }
    int pkh[8], pkl[8];
#pragma unroll
    for (int p = 0; p < 8; p++) {
      pkh[p] = (int)(hi16[2 * p] | (hi16[2 * p + 1] << 16));
      pkl[p] = (int)(lo16[2 * p] | (lo16[2 * p + 1] << 16));
    }
    ushort_t* dst = VI + (size_t)(mn * 64 + cdim) * (2 * L) + (l0 >> 3) * 16;
    *(int4*)dst = make_int4(pkh[0], pkh[1], pkh[2], pkh[3]);
    *(int4*)(dst + 8) = make_int4(pkl[0], pkl[1], pkl[2], pkl[3]);
    *(int4*)(dst + 16) = make_int4(pkh[4], pkh[5], pkh[6], pkh[7]);
    *(int4*)(dst + 24) = make_int4(pkl[4], pkl[5], pkl[6], pkl[7]);

    if (tid < 64) {
      const int l = lseg0 + tid;
      X[mn * L + l] = dm[(size_t)(n * L + l) * 34 + 33];
    }
  }
}

// =================== main attention kernel ===================
// block = one 16-row group, full l-range. Per 64-l chunk all 4 waves DMA the 16KB
// V-slab into double-buffered LDS via global_load_lds (async, coalesced); wave w
// then computes output dims [w*16,(w+1)*16) from ds_read_b128 fragments + MFMA.
// LDS layout XOR-swizzled: global unit (r,g) -> lds unit r*16 + ((g+r)&15).
__device__ inline void stage_chunk(ushort_t* dstbuf, const ushort_t* VIb, int ch,
                                   int w, int lane) {
#pragma unroll
  for (int i = 0; i < 4; i++) {
    const int u = w * 256 + i * 64 + lane;   // lds 16B-unit index this lane fills
    const int rr = u >> 4;                   // dim row 0..63
    const int gs = u & 15;                   // swizzled group slot
    const int g = (gs - rr) & 15;            // original group (8l-halfpair, hi/lo)
    const ushort_t* src = VIb + (size_t)rr * 4096 + ch * 128 + g * 8;
    __builtin_amdgcn_global_load_lds(
        (const __attribute__((address_space(1))) void*)src,
        (__attribute__((address_space(3))) void*)(dstbuf + (size_t)(w * 256 + i * 64) * 8),
        16, 0, 0);
  }
}

__global__ __launch_bounds__(256) void mm_attn_main(
    const ushort_t* __restrict__ VI, const float* __restrict__ X,
    const float* __restrict__ Aq, const float* __restrict__ Gq, const int* __restrict__ Cq,
    float* __restrict__ out) {
  __shared__ ushort_t sbuf[2][8192];  // 2 x 16KB = 32KB exactly -> 5 blocks/CU

  const int b = blockIdx.x;
  const int mn = b % 12;
  const int r = b / 12;  // 0..127
  // heavy rowgroups first (tail blocks are light), pairs interleaved for balance
  const int rg = (r & 1) ? (r >> 1) : (127 - (r >> 1));
  const int tbase = mn * T + rg * 16;

  const int tid = threadIdx.x;
  const int lane = tid & 63;
  const int w = tid >> 6;
  const int q = lane >> 4;
  const int m16 = lane & 15;

  const int c = Cq[tbase + m16];
  const int cmax = __shfl(c, 15, 64);  // c monotone in t
  const int cmin = __shfl(c, 0, 64);
  const int nch = (cmax + 63) >> 6;    // block-uniform

  float a = 0.f, g = 0.f;
  if (nch > 0) { a = Aq[tbase + m16]; g = Gq[tbase + m16]; }

  f32x4 acc = (f32x4){0.f, 0.f, 0.f, 0.f};
  float z = 0.f;

  const ushort_t* VIb = VI + (size_t)mn * 64 * 4096;
  const float* xp = X + mn * L;
  const int rdim = w * 16 + m16;       // this wave's B-fragment dim row

  if (nch > 0) stage_chunk(sbuf[0], VIb, 0, w, lane);
  __syncthreads();

  for (int ch = 0; ch < nch; ch++) {
    const int nb = ch & 1;
    if (ch + 1 < nch) stage_chunk(sbuf[nb ^ 1], VIb, ch + 1, w, lane);

    const int base = ch << 6;
    const ushort_t* buf = sbuf[nb];
#pragma unroll
    for (int hh = 0; hh < 2; hh++) {
      const int k0 = base + hh * 32 + q * 8;
      const float4 xa = *(const float4*)&xp[k0];
      const float4 xb = *(const float4*)&xp[k0 + 4];
      const float xs[8] = {xa.x, xa.y, xa.z, xa.w, xb.x, xb.y, xb.z, xb.w};
      float wv[8];
      if (base + hh * 32 + 32 <= cmin) {  // all 16 rows fully active
#pragma unroll
        for (int j = 0; j < 8; j++) {
          const float d = fmaf(-g, xs[j], a);
          wv[j] = __expf(-d * d);
          z += wv[j];
        }
      } else {
#pragma unroll
        for (int j = 0; j < 8; j++) {
          const float d = fmaf(-g, xs[j], a);
          const float e = __expf(-d * d);
          wv[j] = (k0 + j < c) ? e : 0.f;
          z += wv[j];
        }
      }
      PK8 ph, pl;
#pragma unroll
      for (int p2 = 0; p2 < 4; p2++) {
        const uint u0 = __float_as_uint(wv[2 * p2]);
        const uint u1 = __float_as_uint(wv[2 * p2 + 1]);
        const uint h0 = u0 & 0xffff0000u, h1 = u1 & 0xffff0000u;
        const float l0f = wv[2 * p2] - __uint_as_float(h0);
        const float l1f = wv[2 * p2 + 1] - __uint_as_float(h1);
        ph.i[p2] = (int)((h0 >> 16) | h1);
        pl.i[p2] = (int)((__float_as_uint(l0f) >> 16) | (__float_as_uint(l1f) & 0xffff0000u));
      }
      const bf16x8 ahi = ph.s, alo = pl.s;
      // B fragments from LDS (swizzled): group g0 = (hh*4+q)*2 (+1 for lo)
      const int g0 = (hh * 4 + q) * 2;
      const int uih = rdim * 16 + ((g0 + rdim) & 15);
      const int uil = rdim * 16 + ((g0 + 1 + rdim) & 15);
      const bf16x8 bh = *(const bf16x8*)&buf[(size_t)uih * 8];
      const bf16x8 bl = *(const bf16x8*)&buf[(size_t)uil * 8];
      acc = __builtin_amdgcn_mfma_f32_16x16x32_bf16(ahi, bh, acc, 0, 0, 0);
      acc = __builtin_amdgcn_mfma_f32_16x16x32_bf16(ahi, bl, acc, 0, 0, 0);
      acc = __builtin_amdgcn_mfma_f32_16x16x32_bf16(alo, bh, acc, 0, 0, 0);
    }
    __syncthreads();  // reads of buf done + staging of nb^1 complete
  }

  // z: each lane has partial for row m16 over its q-octets; reduce q-replicas
  z += __shfl_xor(z, 16, 64);
  z += __shfl_xor(z, 32, 64);

  // D layout: col = m16 (dim w*16+m16), row = q*4 + rr
#pragma unroll
  for (int rr2 = 0; rr2 < 4; rr2++) {
    const int row = q * 4 + rr2;
    const float zr = __shfl(z, row, 64);
    const int cr = __shfl(c, row, 64);
    const float inv = 1.0f / (zr + (float)(L - cr));
    out[(size_t)(tbase + row) * 64 + w * 16 + m16] = acc[rr2] * inv;
  }
}

}  // namespace

extern "C" void kernel_launch(void* const* d_in, const int* in_sizes, int n_in,
                              void* d_out, int out_size, void* d_ws, size_t ws_size,
                              hipStream_t stream) {
  const float* ref_data = (const float*)d_in[0];
  const float* ref_t = (const float*)d_in[1];
  const float* m1_data = (const float*)d_in[2];
  const float* m1_t = (const float*)d_in[3];
  const float* m2_data = (const float*)d_in[4];
  const float* m2_t = (const float*)d_in[5];
  const float* m3_data = (const float*)d_in[6];
  const float* m3_t = (const float*)d_in[7];
  const float* Wq = (const float*)d_in[8];
  const float* Wk1 = (const float*)d_in[9];
  const float* bk1 = (const float*)d_in[10];
  const float* Wv1 = (const float*)d_in[11];
  const float* bv1 = (const float*)d_in[12];
  const float* lt1 = (const float*)d_in[13];
  const float* Wk2 = (const float*)d_in[14];
  const float* bk2 = (const float*)d_in[15];
  const float* Wv2 = (const float*)d_in[16];
  const float* bv2 = (const float*)d_in[17];
  const float* lt2 = (const float*)d_in[18];
  const float* Wk3 = (const float*)d_in[19];
  const float* bk3 = (const float*)d_in[20];
  const float* Wv3 = (const float*)d_in[21];
  const float* bv3 = (const float*)d_in[22];
  const float* lt3 = (const float*)d_in[23];

  float* ws = (float*)d_ws;
  ushort_t* VI = (ushort_t*)ws;                 // VI_SZ float slots
  float* Xw = ws + VI_SZ;                       // X_SZ
  float* Aq = Xw + X_SZ;                        // A_SZ
  float* Gq = Aq + A_SZ;                        // A_SZ
  int* Cq = (int*)(Gq + A_SZ);                  // A_SZ

  mm_prep<<<dim3(512), dim3(256), 0, stream>>>(
      ref_data, ref_t, m1_data, m1_t, m2_data, m2_t, m3_data, m3_t, Wq,
      Wk1, bk1, Wv1, bv1, lt1, Wk2, bk2, Wv2, bv2, lt2, Wk3, bk3, Wv3, bv3, lt3,
      Aq, Gq, Cq, VI, Xw);
  mm_attn_main<<<dim3(12 * 128), dim3(256), 0, stream>>>(
      VI, Xw, Aq, Gq, Cq, (float*)d_out);
}

// Round 8
// 171.232 us; speedup vs baseline: 1.1486x; 1.0207x over previous
//
#include <hip/hip_runtime.h>

namespace {

typedef unsigned int uint;
typedef unsigned short ushort_t;
typedef __attribute__((ext_vector_type(8))) short bf16x8;
typedef __attribute__((ext_vector_type(4))) float f32x4;

constexpr int N = 4, T = 2048, L = 2048;
constexpr int DQIN = 32, DQK = 64;

// workspace layout (float-sized slots); ~12.8 MB
constexpr int VI_SZ = 3 * N * 64 * L;  // ushort pairs [dim row][8l-group][hi8|lo8], as float slots
constexpr int X_SZ = 3 * N * L;
constexpr int A_SZ = 3 * N * T;

union PK8 { int i[4]; bf16x8 s; };

// =================== fused prep kernel ===================
// [0,96): Q->a,g (one thread per (m,n,t)); [96,192): binary searches; [192,576): V transform
__global__ __launch_bounds__(256) void mm_prep(
    const float* __restrict__ ref_data, const float* __restrict__ ref_t,
    const float* __restrict__ d1, const float* __restrict__ t1,
    const float* __restrict__ d2, const float* __restrict__ t2,
    const float* __restrict__ d3, const float* __restrict__ t3,
    const float* __restrict__ Wq,
    const float* __restrict__ Wk1, const float* __restrict__ bk1,
    const float* __restrict__ Wv1, const float* __restrict__ bv1, const float* __restrict__ lt1,
    const float* __restrict__ Wk2, const float* __restrict__ bk2,
    const float* __restrict__ Wv2, const float* __restrict__ bv2, const float* __restrict__ lt2,
    const float* __restrict__ Wk3, const float* __restrict__ bk3,
    const float* __restrict__ Wv3, const float* __restrict__ bv3, const float* __restrict__ lt3,
    float* __restrict__ Aq, float* __restrict__ Gq, int* __restrict__ Cq,
    ushort_t* __restrict__ VI, float* __restrict__ X) {
  const int b = blockIdx.x;
  const int tid = threadIdx.x;

  if (b < 96) {
    // ---- Q path, one thread per (m, n*T+t); block-uniform modality m = b/32 ----
    const int m = b >> 5;
    const int idx = (b & 31) * 256 + tid;  // n*T + t
    __shared__ float sWq[DQIN * DQK];
    __shared__ float sWk[DQK];
    __shared__ float sbk[DQK];
    const float* Wk = (m == 0) ? Wk1 : (m == 1 ? Wk2 : Wk3);
    const float* bk = (m == 0) ? bk1 : (m == 1 ? bk2 : bk3);
    const float* lt = (m == 0) ? lt1 : (m == 1 ? lt2 : lt3);
    for (int i = tid; i < DQIN * DQK; i += 256) sWq[i] = Wq[i];
    if (tid < DQK) { sWk[tid] = Wk[tid]; sbk[tid] = bk[tid]; }
    __syncthreads();
    float x[DQIN];
    const float* rp = ref_data + idx * DQIN;
#pragma unroll
    for (int i = 0; i < DQIN; i++) x[i] = rp[i];
    float qr[DQK];
#pragma unroll
    for (int j = 0; j < DQK; j += 4) {
      float4 acc4 = make_float4(0.f, 0.f, 0.f, 0.f);
#pragma unroll
      for (int i = 0; i < DQIN; i++) {
        const float4 w = *(const float4*)&sWq[i * DQK + j];
        acc4.x = fmaf(x[i], w.x, acc4.x);
        acc4.y = fmaf(x[i], w.y, acc4.y);
        acc4.z = fmaf(x[i], w.z, acc4.z);
        acc4.w = fmaf(x[i], w.w, acc4.w);
      }
      qr[j] = acc4.x; qr[j + 1] = acc4.y; qr[j + 2] = acc4.z; qr[j + 3] = acc4.w;
    }
    const float rs = __expf(-0.5f * lt[0]);
    float g = 0.f, h = 0.f;
#pragma unroll
    for (int j = 1; j < DQK; j++) {
      g = fmaf(qr[j], sWk[j - 1], g);
      h = fmaf(qr[j], sbk[j - 1], h);
    }
    g += sWk[DQK - 1];
    h += sbk[DQK - 1];
    Aq[m * (N * T) + idx] = (qr[0] - h) * rs;
    Gq[m * (N * T) + idx] = g * rs;
  } else if (b < 192) {
    const int sidx = (b - 96) * 256 + tid;
    const int m = sidx >> 13;
    const int nt = sidx & 8191;
    const int n = nt >> 11;
    const float rt = ref_t[nt];
    const float* tml = ((m == 0) ? t1 : (m == 1 ? t2 : t3)) + n * L;
    int lo = 0, hi = L;
    while (lo < hi) {
      const int mid = (lo + hi) >> 1;
      if (tml[mid] <= rt) lo = mid + 1; else hi = mid;
    }
    Cq[m * 8192 + nt] = lo;
  } else {
    const int vb = b - 192;          // 0..383
    const int mn = vb >> 5;          // m*N+n
    const int m = mn >> 2, n = mn & 3;
    const int lseg0 = (vb & 31) * 64;
    const float* dm = (m == 0) ? d1 : (m == 1 ? d2 : d3);
    const float* Wv = (m == 0) ? Wv1 : (m == 1 ? Wv2 : Wv3);
    const float* bv = (m == 0) ? bv1 : (m == 1 ? bv2 : bv3);
    const int cdim = tid & 63;
    const int qq = tid >> 6;
    const int l0 = lseg0 + qq * 16;

    float Wc[32];
#pragma unroll
    for (int i = 0; i < 32; i++) Wc[i] = Wv[i * 64 + cdim];
    const float bvc = bv[cdim];

    uint hi16[16], lo16[16];
#pragma unroll 4
    for (int k = 0; k < 16; k++) {
      const float* dp = dm + (size_t)(n * L + l0 + k) * 34;
      float acc = bvc;
#pragma unroll
      for (int i = 0; i < 32; i++) acc = fmaf(dp[i], Wc[i], acc);
      uint u = __float_as_uint(acc);
      uint h = (u + 0x7fffu + ((u >> 16) & 1u)) & 0xffff0000u;
      float res = acc - __uint_as_float(h);
      uint ul = __float_as_uint(res);
      uint hl = (ul + 0x7fffu + ((ul >> 16) & 1u)) >> 16;
      hi16[k] = h >> 16;
      lo16[k] = hl;
    }
    int pkh[8], pkl[8];
#pragma unroll
    for (int p = 0; p < 8; p++) {
      pkh[p] = (int)(hi16[2 * p] | (hi16[2 * p + 1] << 16));
      pkl[p] = (int)(lo16[2 * p] | (lo16[2 * p + 1] << 16));
    }
    ushort_t* dst = VI + (size_t)(mn * 64 + cdim) * (2 * L) + (l0 >> 3) * 16;
    *(int4*)dst = make_int4(pkh[0], pkh[1], pkh[2], pkh[3]);
    *(int4*)(dst + 8) = make_int4(pkl[0], pkl[1], pkl[2], pkl[3]);
    *(int4*)(dst + 16) = make_int4(pkh[4], pkh[5], pkh[6], pkh[7]);
    *(int4*)(dst + 24) = make_int4(pkl[4], pkl[5], pkl[6], pkl[7]);

    if (tid < 64) {
      const int l = lseg0 + tid;
      X[mn * L + l] = dm[(size_t)(n * L + l) * 34 + 33];
    }
  }
}

// =================== main attention kernel ===================
// block = 2 waves, each wave = 16 rows x ALL 64 dims (4 ct MFMA tiles), exp dup=1.
// Rowgroups paired {k, 127-k} so every block has near-identical total work.
// V staged per 64-l chunk (16 KB) into double-buffered LDS via global_load_lds,
// shared by both waves. Weights packed in-register directly in A-fragment layout.
__device__ inline void stage_chunk(ushort_t* dstbuf, const ushort_t* VIb, int ch,
                                   int w, int lane) {
#pragma unroll
  for (int i = 0; i < 8; i++) {
    const int u = w * 512 + i * 64 + lane;   // lds 16B-unit index this lane fills
    const int rr = u >> 4;                   // dim row 0..63
    const int gs = u & 15;                   // swizzled unit slot
    const int g = (gs - rr) & 15;            // original unit (8l-halfpair, hi/lo)
    const ushort_t* src = VIb + (size_t)rr * 4096 + ch * 128 + g * 8;
    __builtin_amdgcn_global_load_lds(
        (const __attribute__((address_space(1))) void*)src,
        (__attribute__((address_space(3))) void*)(dstbuf + (size_t)(w * 512 + i * 64) * 8),
        16, 0, 0);
  }
}

__global__ __launch_bounds__(128) void mm_attn_main(
    const ushort_t* __restrict__ VI, const float* __restrict__ X,
    const float* __restrict__ Aq, const float* __restrict__ Gq, const int* __restrict__ Cq,
    float* __restrict__ out) {
  __shared__ ushort_t sbuf[2][8192];  // 2 x 16KB = 32KB -> 5 blocks/CU

  const int b = blockIdx.x;
  const int mn = b % 12;
  const int k = b / 12;  // 0..63

  const int tid = threadIdx.x;
  const int lane = tid & 63;
  const int w = tid >> 6;              // wave 0/1
  const int q = lane >> 4;
  const int m16 = lane & 15;

  const int rg = (w == 0) ? k : (127 - k);   // paired rowgroups: c_k + c_{127-k} ~ const
  const int tbase = mn * T + rg * 16;

  const int c = Cq[tbase + m16];
  const int cmax = __shfl(c, 15, 64);  // c monotone in t
  const int cmin = __shfl(c, 0, 64);
  const int nch = (cmax + 63) >> 6;    // this wave's chunk count

  // block-uniform chunk count = wave 1's (rg 127-k always has the larger c)
  const int cB = Cq[mn * T + (127 - k) * 16 + 15];
  const int nchB = (cB + 63) >> 6;

  const float a = Aq[tbase + m16];
  const float g = Gq[tbase + m16];

  f32x4 acc[4];
#pragma unroll
  for (int ct = 0; ct < 4; ct++) acc[ct] = (f32x4){0.f, 0.f, 0.f, 0.f};
  float z = 0.f;

  const ushort_t* VIb = VI + (size_t)mn * 64 * 4096;
  const float* xp = X + mn * L;

  stage_chunk(sbuf[0], VIb, 0, w, lane);
  __syncthreads();

  for (int ch = 0; ch < nchB; ch++) {
    const int nb = ch & 1;
    if (ch + 1 < nchB) stage_chunk(sbuf[nb ^ 1], VIb, ch + 1, w, lane);

    if (ch < nch) {
      const int base = ch << 6;
      const ushort_t* buf = sbuf[nb];
      const bool inter = (base + 64 <= cmin);  // all 16 rows fully active
#pragma unroll
      for (int kk = 0; kk < 2; kk++) {
        const int k0 = base + kk * 32 + q * 8;
        const float4 xa = *(const float4*)&xp[k0];
        const float4 xb = *(const float4*)&xp[k0 + 4];
        const float xs[8] = {xa.x, xa.y, xa.z, xa.w, xb.x, xb.y, xb.z, xb.w};
        float wv[8];
        if (inter) {
#pragma unroll
          for (int j = 0; j < 8; j++) {
            const float d = fmaf(-g, xs[j], a);
            wv[j] = __expf(-d * d);
            z += wv[j];
          }
        } else {
#pragma unroll
          for (int j = 0; j < 8; j++) {
            const float d = fmaf(-g, xs[j], a);
            const float e = __expf(-d * d);
            wv[j] = (k0 + j < c) ? e : 0.f;
            z += wv[j];
          }
        }
        PK8 ph, pl;
#pragma unroll
        for (int p2 = 0; p2 < 4; p2++) {
          const uint u0 = __float_as_uint(wv[2 * p2]);
          const uint u1 = __float_as_uint(wv[2 * p2 + 1]);
          const uint h0 = u0 & 0xffff0000u, h1 = u1 & 0xffff0000u;
          const float l0f = wv[2 * p2] - __uint_as_float(h0);
          const float l1f = wv[2 * p2 + 1] - __uint_as_float(h1);
          ph.i[p2] = (int)((h0 >> 16) | h1);
          pl.i[p2] = (int)((__float_as_uint(l0f) >> 16) | (__float_as_uint(l1f) & 0xffff0000u));
        }
        const bf16x8 ahi = ph.s, alo = pl.s;
#pragma unroll
        for (int ct = 0; ct < 4; ct++) {
          const int r = ct * 16 + m16;                 // V dim row
          const int go = (kk * 4 + q) * 2;             // unit-in-row (hi)
          const int uih = r * 16 + ((go + r) & 15);
          const int uil = r * 16 + ((go + 1 + r) & 15);
          const bf16x8 bh = *(const bf16x8*)&buf[(size_t)uih * 8];
          const bf16x8 bl = *(const bf16x8*)&buf[(size_t)uil * 8];
          acc[ct] = __builtin_amdgcn_mfma_f32_16x16x32_bf16(ahi, bh, acc[ct], 0, 0, 0);
          acc[ct] = __builtin_amdgcn_mfma_f32_16x16x32_bf16(ahi, bl, acc[ct], 0, 0, 0);
          acc[ct] = __builtin_amdgcn_mfma_f32_16x16x32_bf16(alo, bh, acc[ct], 0, 0, 0);
        }
      }
    }
    __syncthreads();  // reads of buf done + staging of nb^1 complete
  }

  // z: reduce q-replicas (each octet covered disjoint l)
  z += __shfl_xor(z, 16, 64);
  z += __shfl_xor(z, 32, 64);

  // D layout per ct: col = ct*16 + m16, row = q*4 + rr
#pragma unroll
  for (int rr = 0; rr < 4; rr++) {
    const int row = q * 4 + rr;
    const float zr = __shfl(z, row, 64);
    const int cr = __shfl(c, row, 64);
    const float inv = 1.0f / (zr + (float)(L - cr));
#pragma unroll
    for (int ct = 0; ct < 4; ct++) {
      out[(size_t)(tbase + row) * 64 + ct * 16 + m16] = acc[ct][rr] * inv;
    }
  }
}

}  // namespace

extern "C" void kernel_launch(void* const* d_in, const int* in_sizes, int n_in,
                              void* d_out, int out_size, void* d_ws, size_t ws_size,
                              hipStream_t stream) {
  const float* ref_data = (const float*)d_in[0];
  const float* ref_t = (const float*)d_in[1];
  const float* m1_data = (const float*)d_in[2];
  const float* m1_t = (const float*)d_in[3];
  const float* m2_data = (const float*)d_in[4];
  const float* m2_t = (const float*)d_in[5];
  const float* m3_data = (const float*)d_in[6];
  const float* m3_t = (const float*)d_in[7];
  const float* Wq = (const float*)d_in[8];
  const float* Wk1 = (const float*)d_in[9];
  const float* bk1 = (const float*)d_in[10];
  const float* Wv1 = (const float*)d_in[11];
  const float* bv1 = (const float*)d_in[12];
  const float* lt1 = (const float*)d_in[13];
  const float* Wk2 = (const float*)d_in[14];
  const float* bk2 = (const float*)d_in[15];
  const float* Wv2 = (const float*)d_in[16];
  const float* bv2 = (const float*)d_in[17];
  const float* lt2 = (const float*)d_in[18];
  const float* Wk3 = (const float*)d_in[19];
  const float* bk3 = (const float*)d_in[20];
  const float* Wv3 = (const float*)d_in[21];
  const float* bv3 = (const float*)d_in[22];
  const float* lt3 = (const float*)d_in[23];

  float* ws = (float*)d_ws;
  ushort_t* VI = (ushort_t*)ws;                 // VI_SZ float slots
  float* Xw = ws + VI_SZ;                       // X_SZ
  float* Aq = Xw + X_SZ;                        // A_SZ
  float* Gq = Aq + A_SZ;                        // A_SZ
  int* Cq = (int*)(Gq + A_SZ);                  // A_SZ

  mm_prep<<<dim3(576), dim3(256), 0, stream>>>(
      ref_data, ref_t, m1_data, m1_t, m2_data, m2_t, m3_data, m3_t, Wq,
      Wk1, bk1, Wv1, bv1, lt1, Wk2, bk2, Wv2, bv2, lt2, Wk3, bk3, Wv3, bv3, lt3,
      Aq, Gq, Cq, VI, Xw);
  mm_attn_main<<<dim3(12 * 64), dim3(128), 0, stream>>>(
      VI, Xw, Aq, Gq, Cq, (float*)d_out);
}

// Round 9
// 148.829 us; speedup vs baseline: 1.3215x; 1.1505x over previous
//
#include <hip/hip_runtime.h>

namespace {

typedef unsigned int uint;
typedef unsigned short ushort_t;
typedef __attribute__((ext_vector_type(8))) short bf16x8;
typedef __attribute__((ext_vector_type(4))) float f32x4;

constexpr int N = 4, T = 2048, L = 2048;
constexpr int DQIN = 32, DQK = 64;

// workspace layout (float-sized slots); ~12.8 MB
constexpr int VI_SZ = 3 * N * 64 * L;  // ushort pairs [dim row][8l-group][hi8|lo8], as float slots
constexpr int X_SZ = 3 * N * L;
constexpr int A_SZ = 3 * N * T;

union PK8 { int i[4]; bf16x8 s; };

// =================== fused prep kernel ===================
// [0,96): Q->a,g (one thread per (m,n,t)); [96,192): binary searches; [192,576): V transform
__global__ __launch_bounds__(256) void mm_prep(
    const float* __restrict__ ref_data, const float* __restrict__ ref_t,
    const float* __restrict__ d1, const float* __restrict__ t1,
    const float* __restrict__ d2, const float* __restrict__ t2,
    const float* __restrict__ d3, const float* __restrict__ t3,
    const float* __restrict__ Wq,
    const float* __restrict__ Wk1, const float* __restrict__ bk1,
    const float* __restrict__ Wv1, const float* __restrict__ bv1, const float* __restrict__ lt1,
    const float* __restrict__ Wk2, const float* __restrict__ bk2,
    const float* __restrict__ Wv2, const float* __restrict__ bv2, const float* __restrict__ lt2,
    const float* __restrict__ Wk3, const float* __restrict__ bk3,
    const float* __restrict__ Wv3, const float* __restrict__ bv3, const float* __restrict__ lt3,
    float* __restrict__ Aq, float* __restrict__ Gq, int* __restrict__ Cq,
    ushort_t* __restrict__ VI, float* __restrict__ X) {
  const int b = blockIdx.x;
  const int tid = threadIdx.x;

  if (b < 96) {
    // ---- Q path, one thread per (m, n*T+t); block-uniform modality m = b/32 ----
    const int m = b >> 5;
    const int idx = (b & 31) * 256 + tid;  // n*T + t
    __shared__ float sWq[DQIN * DQK];
    __shared__ float sWk[DQK];
    __shared__ float sbk[DQK];
    const float* Wk = (m == 0) ? Wk1 : (m == 1 ? Wk2 : Wk3);
    const float* bk = (m == 0) ? bk1 : (m == 1 ? bk2 : bk3);
    const float* lt = (m == 0) ? lt1 : (m == 1 ? lt2 : lt3);
    for (int i = tid; i < DQIN * DQK; i += 256) sWq[i] = Wq[i];
    if (tid < DQK) { sWk[tid] = Wk[tid]; sbk[tid] = bk[tid]; }
    __syncthreads();
    float x[DQIN];
    const float* rp = ref_data + idx * DQIN;
#pragma unroll
    for (int i = 0; i < DQIN; i++) x[i] = rp[i];
    float qr[DQK];
#pragma unroll
    for (int j = 0; j < DQK; j += 4) {
      float4 acc4 = make_float4(0.f, 0.f, 0.f, 0.f);
#pragma unroll
      for (int i = 0; i < DQIN; i++) {
        const float4 w = *(const float4*)&sWq[i * DQK + j];
        acc4.x = fmaf(x[i], w.x, acc4.x);
        acc4.y = fmaf(x[i], w.y, acc4.y);
        acc4.z = fmaf(x[i], w.z, acc4.z);
        acc4.w = fmaf(x[i], w.w, acc4.w);
      }
      qr[j] = acc4.x; qr[j + 1] = acc4.y; qr[j + 2] = acc4.z; qr[j + 3] = acc4.w;
    }
    const float rs = __expf(-0.5f * lt[0]);
    float g = 0.f, h = 0.f;
#pragma unroll
    for (int j = 1; j < DQK; j++) {
      g = fmaf(qr[j], sWk[j - 1], g);
      h = fmaf(qr[j], sbk[j - 1], h);
    }
    g += sWk[DQK - 1];
    h += sbk[DQK - 1];
    Aq[m * (N * T) + idx] = (qr[0] - h) * rs;
    Gq[m * (N * T) + idx] = g * rs;
  } else if (b < 192) {
    const int sidx = (b - 96) * 256 + tid;
    const int m = sidx >> 13;
    const int nt = sidx & 8191;
    const int n = nt >> 11;
    const float rt = ref_t[nt];
    const float* tml = ((m == 0) ? t1 : (m == 1 ? t2 : t3)) + n * L;
    int lo = 0, hi = L;
    while (lo < hi) {
      const int mid = (lo + hi) >> 1;
      if (tml[mid] <= rt) lo = mid + 1; else hi = mid;
    }
    Cq[m * 8192 + nt] = lo;
  } else {
    const int vb = b - 192;          // 0..383
    const int mn = vb >> 5;          // m*N+n
    const int m = mn >> 2, n = mn & 3;
    const int lseg0 = (vb & 31) * 64;
    const float* dm = (m == 0) ? d1 : (m == 1 ? d2 : d3);
    const float* Wv = (m == 0) ? Wv1 : (m == 1 ? Wv2 : Wv3);
    const float* bv = (m == 0) ? bv1 : (m == 1 ? bv2 : bv3);
    const int cdim = tid & 63;
    const int qq = tid >> 6;
    const int l0 = lseg0 + qq * 16;

    float Wc[32];
#pragma unroll
    for (int i = 0; i < 32; i++) Wc[i] = Wv[i * 64 + cdim];
    const float bvc = bv[cdim];

    uint hi16[16], lo16[16];
#pragma unroll 4
    for (int k = 0; k < 16; k++) {
      const float* dp = dm + (size_t)(n * L + l0 + k) * 34;
      float acc = bvc;
#pragma unroll
      for (int i = 0; i < 32; i++) acc = fmaf(dp[i], Wc[i], acc);
      uint u = __float_as_uint(acc);
      uint h = (u + 0x7fffu + ((u >> 16) & 1u)) & 0xffff0000u;
      float res = acc - __uint_as_float(h);
      uint ul = __float_as_uint(res);
      uint hl = (ul + 0x7fffu + ((ul >> 16) & 1u)) >> 16;
      hi16[k] = h >> 16;
      lo16[k] = hl;
    }
    int pkh[8], pkl[8];
#pragma unroll
    for (int p = 0; p < 8; p++) {
      pkh[p] = (int)(hi16[2 * p] | (hi16[2 * p + 1] << 16));
      pkl[p] = (int)(lo16[2 * p] | (lo16[2 * p + 1] << 16));
    }
    ushort_t* dst = VI + (size_t)(mn * 64 + cdim) * (2 * L) + (l0 >> 3) * 16;
    *(int4*)dst = make_int4(pkh[0], pkh[1], pkh[2], pkh[3]);
    *(int4*)(dst + 8) = make_int4(pkl[0], pkl[1], pkl[2], pkl[3]);
    *(int4*)(dst + 16) = make_int4(pkh[4], pkh[5], pkh[6], pkh[7]);
    *(int4*)(dst + 24) = make_int4(pkl[4], pkl[5], pkl[6], pkl[7]);

    if (tid < 64) {
      const int l = lseg0 + tid;
      X[mn * L + l] = dm[(size_t)(n * L + l) * 34 + 33];
    }
  }
}

// =================== main attention kernel ===================
// block = 2 waves x 32 output dims (dh selects dim half). Wave w handles rowgroup
// {k} (w=0) or {127-k} (w=1) -- paired so block work is ~constant. Per 64-l chunk
// the block stages an 8 KB V-slab (32 dim rows, hi+lo interleaved) into
// double-buffered LDS via global_load_lds; X is cached in LDS once per block.
// Weights packed in-register directly in A-fragment layout; exp dup = 2 (dim halves),
// traded for 6 blocks/CU = 12 waves/CU concurrency.
__device__ inline void stage_chunk(ushort_t* dstbuf, const ushort_t* VIb, int ch,
                                   int w, int lane) {
#pragma unroll
  for (int i = 0; i < 4; i++) {
    const int u = (w * 4 + i) * 64 + lane;   // 16B-unit index 0..511
    const int lr = u >> 4;                   // local dim row 0..31
    const int gs = u & 15;                   // swizzled unit slot
    const int g = (gs - lr) & 15;            // original unit (8l-halfpair, hi/lo)
    const ushort_t* src = VIb + (size_t)lr * 4096 + ch * 128 + g * 8;
    __builtin_amdgcn_global_load_lds(
        (const __attribute__((address_space(1))) void*)src,
        (__attribute__((address_space(3))) void*)(dstbuf + (w * 4 + i) * 512),
        16, 0, 0);
  }
}

__global__ __launch_bounds__(128, 3) void mm_attn_main(
    const ushort_t* __restrict__ VI, const float* __restrict__ X,
    const float* __restrict__ Aq, const float* __restrict__ Gq, const int* __restrict__ Cq,
    float* __restrict__ out) {
  __shared__ ushort_t sbuf[2][4096];  // 2 x 8KB V slabs
  __shared__ float sx[2048];          // full X row for this mn (8KB)  -> 24KB total

  const int b = blockIdx.x;
  const int mn = b % 12;
  const int r = b / 12;   // 0..127
  const int k = r >> 1;   // 0..63
  const int dh = r & 1;   // dim half

  const int tid = threadIdx.x;
  const int lane = tid & 63;
  const int w = tid >> 6;              // wave 0/1
  const int q = lane >> 4;
  const int m16 = lane & 15;

  const int rg = (w == 0) ? k : (127 - k);   // paired rowgroups: c_k + c_{127-k} ~ const
  const int tbase = mn * T + rg * 16;

  const int c = Cq[tbase + m16];
  const int cmax = __shfl(c, 15, 64);  // c monotone in t
  const int cmin = __shfl(c, 0, 64);
  const int nch = (cmax + 63) >> 6;    // this wave's chunk count

  // block-uniform chunk count = rowgroup 127-k's (always the larger c)
  const int cB = Cq[mn * T + (127 - k) * 16 + 15];
  const int nchB = (cB + 63) >> 6;

  const float a = Aq[tbase + m16];
  const float g = Gq[tbase + m16];

  f32x4 acc[2];
  acc[0] = (f32x4){0.f, 0.f, 0.f, 0.f};
  acc[1] = (f32x4){0.f, 0.f, 0.f, 0.f};
  float z = 0.f;

  const ushort_t* VIb = VI + (size_t)(mn * 64 + dh * 32) * 4096;
  const float* xg = X + mn * L;

  // hoisted swizzled B-fragment offsets (shorts), loop-invariant per lane:
  // unit (lr, gg) at lr*16 + ((gg+lr)&15); gg = kk*8 + q*2 + hl
  int oh[2][2], ol[2][2];
#pragma unroll
  for (int ct = 0; ct < 2; ct++) {
#pragma unroll
    for (int kk = 0; kk < 2; kk++) {
      const int lr = ct * 16 + m16;
      oh[ct][kk] = lr * 128 + (((kk * 8 + q * 2 + 0) + lr) & 15) * 8;
      ol[ct][kk] = lr * 128 + (((kk * 8 + q * 2 + 1) + lr) & 15) * 8;
    }
  }

  // stage X (8 instrs of 1KB across the block) + first V chunk
#pragma unroll
  for (int i = 0; i < 4; i++) {
    const float* src = xg + (w * 4 + i) * 256 + lane * 4;
    __builtin_amdgcn_global_load_lds(
        (const __attribute__((address_space(1))) void*)src,
        (__attribute__((address_space(3))) void*)(sx + (w * 4 + i) * 256),
        16, 0, 0);
  }
  stage_chunk(sbuf[0], VIb, 0, w, lane);
  __syncthreads();

  for (int ch = 0; ch < nchB; ch++) {
    const int nb = ch & 1;
    if (ch + 1 < nchB) stage_chunk(sbuf[nb ^ 1], VIb, ch + 1, w, lane);

    if (ch < nch) {
      const int base = ch << 6;
      const ushort_t* buf = sbuf[nb];
      const bool inter = (base + 64 <= cmin);  // all 16 rows fully active
#pragma unroll
      for (int kk = 0; kk < 2; kk++) {
        const int k0 = base + kk * 32 + q * 8;
        const float4 xa = *(const float4*)&sx[k0];
        const float4 xb = *(const float4*)&sx[k0 + 4];
        const float xs[8] = {xa.x, xa.y, xa.z, xa.w, xb.x, xb.y, xb.z, xb.w};
        float wv[8];
        if (inter) {
#pragma unroll
          for (int j = 0; j < 8; j++) {
            const float d = fmaf(-g, xs[j], a);
            wv[j] = __expf(-d * d);
            z += wv[j];
          }
        } else {
#pragma unroll
          for (int j = 0; j < 8; j++) {
            const float d = fmaf(-g, xs[j], a);
            const float e = __expf(-d * d);
            wv[j] = (k0 + j < c) ? e : 0.f;
            z += wv[j];
          }
        }
        PK8 ph, pl;
#pragma unroll
        for (int p2 = 0; p2 < 4; p2++) {
          const uint u0 = __float_as_uint(wv[2 * p2]);
          const uint u1 = __float_as_uint(wv[2 * p2 + 1]);
          const uint h0 = u0 & 0xffff0000u, h1 = u1 & 0xffff0000u;
          const float l0f = wv[2 * p2] - __uint_as_float(h0);
          const float l1f = wv[2 * p2 + 1] - __uint_as_float(h1);
          ph.i[p2] = (int)((h0 >> 16) | h1);
          pl.i[p2] = (int)((__float_as_uint(l0f) >> 16) | (__float_as_uint(l1f) & 0xffff0000u));
        }
        const bf16x8 ahi = ph.s, alo = pl.s;
#pragma unroll
        for (int ct = 0; ct < 2; ct++) {
          const bf16x8 bh = *(const bf16x8*)(buf + oh[ct][kk]);
          const bf16x8 bl = *(const bf16x8*)(buf + ol[ct][kk]);
          acc[ct] = __builtin_amdgcn_mfma_f32_16x16x32_bf16(ahi, bh, acc[ct], 0, 0, 0);
          acc[ct] = __builtin_amdgcn_mfma_f32_16x16x32_bf16(ahi, bl, acc[ct], 0, 0, 0);
          acc[ct] = __builtin_amdgcn_mfma_f32_16x16x32_bf16(alo, bh, acc[ct], 0, 0, 0);
        }
      }
    }
    __syncthreads();  // reads of buf done + staging of nb^1 complete
  }

  // z: reduce q-replicas (each octet covered disjoint l)
  z += __shfl_xor(z, 16, 64);
  z += __shfl_xor(z, 32, 64);

  // D layout per ct: col = dh*32 + ct*16 + m16, row = q*4 + rr
#pragma unroll
  for (int rr = 0; rr < 4; rr++) {
    const int row = q * 4 + rr;
    const float zr = __shfl(z, row, 64);
    const int cr = __shfl(c, row, 64);
    const float inv = 1.0f / (zr + (float)(L - cr));
#pragma unroll
    for (int ct = 0; ct < 2; ct++) {
      out[(size_t)(tbase + row) * 64 + dh * 32 + ct * 16 + m16] = acc[ct][rr] * inv;
    }
  }
}

}  // namespace

extern "C" void kernel_launch(void* const* d_in, const int* in_sizes, int n_in,
                              void* d_out, int out_size, void* d_ws, size_t ws_size,
                              hipStream_t stream) {
  const float* ref_data = (const float*)d_in[0];
  const float* ref_t = (const float*)d_in[1];
  const float* m1_data = (const float*)d_in[2];
  const float* m1_t = (const float*)d_in[3];
  const float* m2_data = (const float*)d_in[4];
  const float* m2_t = (const float*)d_in[5];
  const float* m3_data = (const float*)d_in[6];
  const float* m3_t = (const float*)d_in[7];
  const float* Wq = (const float*)d_in[8];
  const float* Wk1 = (const float*)d_in[9];
  const float* bk1 = (const float*)d_in[10];
  const float* Wv1 = (const float*)d_in[11];
  const float* bv1 = (const float*)d_in[12];
  const float* lt1 = (const float*)d_in[13];
  const float* Wk2 = (const float*)d_in[14];
  const float* bk2 = (const float*)d_in[15];
  const float* Wv2 = (const float*)d_in[16];
  const float* bv2 = (const float*)d_in[17];
  const float* lt2 = (const float*)d_in[18];
  const float* Wk3 = (const float*)d_in[19];
  const float* bk3 = (const float*)d_in[20];
  const float* Wv3 = (const float*)d_in[21];
  const float* bv3 = (const float*)d_in[22];
  const float* lt3 = (const float*)d_in[23];

  float* ws = (float*)d_ws;
  ushort_t* VI = (ushort_t*)ws;                 // VI_SZ float slots
  float* Xw = ws + VI_SZ;                       // X_SZ
  float* Aq = Xw + X_SZ;                        // A_SZ
  float* Gq = Aq + A_SZ;                        // A_SZ
  int* Cq = (int*)(Gq + A_SZ);                  // A_SZ

  mm_prep<<<dim3(576), dim3(256), 0, stream>>>(
      ref_data, ref_t, m1_data, m1_t, m2_data, m2_t, m3_data, m3_t, Wq,
      Wk1, bk1, Wv1, bv1, lt1, Wk2, bk2, Wv2, bv2, lt2, Wk3, bk3, Wv3, bv3, lt3,
      Aq, Gq, Cq, VI, Xw);
  mm_attn_main<<<dim3(12 * 64 * 2), dim3(128), 0, stream>>>(
      VI, Xw, Aq, Gq, Cq, (float*)d_out);
}